// Round 2
// baseline (332.357 us; speedup 1.0000x reference)
//
#include <hip/hip_runtime.h>

// DeepSeek MoE gate, fused: logits GEMM (f16 split-precision MFMA, 3 passes)
// + sigmoid+bias + group-limited top-k epilogue.
// Round 2: B operand bypasses LDS — loaded as pre-packed MFMA fragments
// (fragment-major Wf layout) straight from global/L2. LDS holds only the
// 32x128 A tile (hi/lo) + scores overlay. BM=32 -> grid 512 -> 2 WGs/CU.

#define TTOK 16384
#define EEXP 256
#define HDIM 7168
#define BM 32
#define BK 128
#define NSTEP (HDIM / BK)   // 56
#define NTHR 256
#define NKC (HDIM / 32)     // 224 k-chunks of 32
#define LDS_BYTES 33024     // max(A hi+lo 16K, scores 32x257x4 = 32896)

typedef __attribute__((ext_vector_type(4))) float f32x4;
typedef __attribute__((ext_vector_type(4))) _Float16 h4;
typedef __attribute__((ext_vector_type(8))) _Float16 h8;

// ---------------------------------------------------------------------------
// Kernel 1: W[256][7168] f32 -> fragment-major f16 hi/lo tables.
// Wf[eb][kc][lane] holds 8 f16: expert = eb*16 + (lane&15),
// k = kc*32 + (lane>>4)*8 + j  — exactly the 16x16x32 MFMA B-fragment.
// ---------------------------------------------------------------------------
__global__ __launch_bounds__(64) void pack_w_kernel(const float* __restrict__ W,
                                                    _Float16* __restrict__ whi,
                                                    _Float16* __restrict__ wlo) {
  const int kc = blockIdx.x;     // 0..223
  const int eb = blockIdx.y;     // 0..15
  const int lane = threadIdx.x;  // 0..63
  const int e = eb * 16 + (lane & 15);
  const int k0 = kc * 32 + (lane >> 4) * 8;
  const float* src = W + (size_t)e * HDIM + k0;
  h8 hi, lo;
#pragma unroll
  for (int j = 0; j < 8; ++j) {
    float x = src[j];
    _Float16 h = (_Float16)x;
    hi[j] = h;
    lo[j] = (_Float16)((x - (float)h) * 2048.0f);  // exact residual, scaled out of denormals
  }
  const size_t fi = ((size_t)(eb * NKC + kc) * 64 + lane) * 8;
  *(h8*)(whi + fi) = hi;
  *(h8*)(wlo + fi) = lo;
}

// ---------------------------------------------------------------------------
// Kernel 2: fused gate. One WG = 32 tokens x 256 experts. 4 waves (1x4).
// ---------------------------------------------------------------------------
__global__ __launch_bounds__(NTHR) void gate_kernel(
    const float* __restrict__ X, const _Float16* __restrict__ Whi,
    const _Float16* __restrict__ Wlo, const float* __restrict__ bias,
    float* __restrict__ outw, float* __restrict__ outi) {
  extern __shared__ char smem[];
  _Float16* Ahi = (_Float16*)smem;             // [32][128] f16, chunk-swizzled
  _Float16* Alo = (_Float16*)(smem + 8192);    // [32][128]
  float (*scores)[EEXP + 1] = (float (*)[EEXP + 1])smem;  // [32][257], overlays A

  const int tid = threadIdx.x;
  const int lane = tid & 63;
  const int wid = tid >> 6;        // 0..3 : 64-expert stripe
  const int webase = wid * 4;      // expert-block (of 16) base
  const int tok0 = blockIdx.x * BM;

  f32x4 ra[4];            // staged A (f32), 4 float4 per thread
  h8 bh0[4], bl0[4];      // B fragment ping buffer (4 expert-blocks)
  h8 bh1[4], bl1[4];      // B fragment pong buffer

  f32x4 acc1[2][4], acc2[2][4];
#pragma unroll
  for (int m = 0; m < 2; ++m)
#pragma unroll
    for (int n = 0; n < 4; ++n) {
      acc1[m][n] = (f32x4){0.f, 0.f, 0.f, 0.f};
      acc2[m][n] = (f32x4){0.f, 0.f, 0.f, 0.f};
    }

  auto LOADA = [&](int k0) {
#pragma unroll
    for (int i = 0; i < 4; ++i) {
      const int p = tid + i * 256;  // f32x4 id; row = p>>5, quad q = p&31
      ra[i] = *(const f32x4*)(X + (size_t)(tok0 + (p >> 5)) * HDIM + k0 + (p & 31) * 4);
    }
  };

  auto STOREA = [&]() {
#pragma unroll
    for (int i = 0; i < 4; ++i) {
      const int p = tid + i * 256;
      const int row = p >> 5, q = p & 31;
      h4 hi, lo;
#pragma unroll
      for (int j = 0; j < 4; ++j) {
        float x = ra[i][j];
        _Float16 h = (_Float16)x;
        hi[j] = h;
        lo[j] = (_Float16)((x - (float)h) * 2048.0f);
      }
      // 16B chunk cc = q>>1 (0..15), swizzle: cc ^= row&15 (row stride 256B)
      const int ix = row * BK + (((q >> 1) ^ (row & 15)) << 3) + (q & 1) * 4;
      *(h4*)(Ahi + ix) = hi;
      *(h4*)(Alo + ix) = lo;
    }
  };

#define BLOAD(BH, BL, KC)                                              \
  {                                                                    \
    const int kc_ = (KC);                                              \
    _Pragma("unroll") for (int n = 0; n < 4; ++n) {                    \
      const long fi_ = ((long)(webase + n) * NKC + kc_) * 64 + lane;   \
      BH[n] = *(const h8*)(Whi + fi_ * 8);                             \
      BL[n] = *(const h8*)(Wlo + fi_ * 8);                             \
    }                                                                  \
  }

#define PHASE(S, BH, BL)                                                        \
  {                                                                             \
    h8 ah[2], al[2];                                                            \
    _Pragma("unroll") for (int m = 0; m < 2; ++m) {                             \
      const int r_ = m * 16 + (lane & 15);                                      \
      const int cc_ = (S) * 4 + (lane >> 4);                                    \
      const int ix_ = r_ * BK + ((cc_ ^ (r_ & 15)) << 3);                       \
      ah[m] = *(h8*)(Ahi + ix_);                                                \
      al[m] = *(h8*)(Alo + ix_);                                                \
    }                                                                           \
    _Pragma("unroll") for (int n = 0; n < 4; ++n)                               \
        _Pragma("unroll") for (int m = 0; m < 2; ++m) {                         \
      acc1[m][n] = __builtin_amdgcn_mfma_f32_16x16x32_f16(ah[m], BH[n], acc1[m][n], 0, 0, 0); \
      acc2[m][n] = __builtin_amdgcn_mfma_f32_16x16x32_f16(ah[m], BL[n], acc2[m][n], 0, 0, 0); \
      acc2[m][n] = __builtin_amdgcn_mfma_f32_16x16x32_f16(al[m], BH[n], acc2[m][n], 0, 0, 0); \
    }                                                                           \
  }

  LOADA(0);
  BLOAD(bh0, bl0, 0);
#pragma unroll 1
  for (int kk = 0; kk < NSTEP; ++kk) {
    __syncthreads();  // previous compute's A ds_reads done
    STOREA();
    __syncthreads();
    if (kk + 1 < NSTEP) LOADA((kk + 1) * BK);  // HBM latency hides under MFMA
    const int kcb = kk * 4;
    BLOAD(bh1, bl1, kcb + 1);
    PHASE(0, bh0, bl0);
    BLOAD(bh0, bl0, kcb + 2);
    PHASE(1, bh1, bl1);
    BLOAD(bh1, bl1, kcb + 3);
    PHASE(2, bh0, bl0);
    if (kk + 1 < NSTEP) { BLOAD(bh0, bl0, kcb + 4); }  // next step's kc0
    PHASE(3, bh1, bl1);
  }

  __syncthreads();  // last A ds_reads done before scores overlay

  // scores = sigmoid(logit) + bias  -> LDS [32][257]
  // C/D layout: col = lane&15, row = (lane>>4)*4 + reg
  const int ebase = wid * 64;
#pragma unroll
  for (int m = 0; m < 2; ++m)
#pragma unroll
    for (int n = 0; n < 4; ++n) {
      const int e = ebase + n * 16 + (lane & 15);
      const float b = bias[e];
      const int t0 = m * 16 + (lane >> 4) * 4;
#pragma unroll
      for (int r = 0; r < 4; ++r) {
        const float logit = acc1[m][n][r] + acc2[m][n][r] * (1.0f / 2048.0f);
        scores[t0 + r][e] = 1.0f / (1.0f + expf(-logit)) + b;
      }
    }
  __syncthreads();

  // Per-token top-k: 8 tokens per wave, one active lane per token (32 total).
  if ((lane & 7) == 0) {
    const int t = wid * 8 + (lane >> 3);  // 0..31
    const float* sc = scores[t];

    float gmax[8];
#pragma unroll
    for (int g = 0; g < 8; ++g) {
      float mx = -1e30f;
      for (int j = 0; j < 32; ++j) mx = fmaxf(mx, sc[g * 32 + j]);
      gmax[g] = mx;
    }
    // top-4 groups (strict > keeps lowest index on ties, matching lax.top_k)
    unsigned selmask = 0;
    for (int it = 0; it < 4; ++it) {
      float best = -1e30f;
      int bi = 0;
      for (int g = 0; g < 8; ++g)
        if (!((selmask >> g) & 1) && gmax[g] > best) {
          best = gmax[g];
          bi = g;
        }
      selmask |= 1u << bi;
    }
    // stable top-8 over masked scores (masked-out groups contribute 0.0)
    float vals[8];
    int idx[8];
#pragma unroll
    for (int j = 0; j < 8; ++j) {
      vals[j] = -1e30f;
      idx[j] = 0;
    }
    for (int e = 0; e < 256; ++e) {
      float v = ((selmask >> (e >> 5)) & 1) ? sc[e] : 0.0f;
      if (v > vals[7]) {
        int p = 7;
        while (p > 0 && v > vals[p - 1]) {
          vals[p] = vals[p - 1];
          idx[p] = idx[p - 1];
          --p;
        }
        vals[p] = v;
        idx[p] = e;
      }
    }
    float ssum = 0.0f;
#pragma unroll
    for (int j = 0; j < 8; ++j) ssum += vals[j];
    const float den = ssum + 1e-6f;
    const long tg = (long)tok0 + t;
#pragma unroll
    for (int j = 0; j < 8; ++j) {
      outw[tg * 8 + j] = vals[j] / den;
      outi[tg * 8 + j] = (float)idx[j];  // indices written as f32 values
    }
  }
}

extern "C" void kernel_launch(void* const* d_in, const int* in_sizes, int n_in,
                              void* d_out, int out_size, void* d_ws, size_t ws_size,
                              hipStream_t stream) {
  const float* X = (const float*)d_in[0];     // [16384,7168] f32
  const float* W = (const float*)d_in[1];     // [256,7168] f32
  const float* bias = (const float*)d_in[2];  // [256] f32

  _Float16* whi = (_Float16*)d_ws;
  _Float16* wlo = whi + (size_t)EEXP * HDIM;  // 7.34 MB of ws total

  float* outw = (float*)d_out;            // [16384,8]
  float* outi = outw + (size_t)TTOK * 8;  // [16384,8] as f32 values

  hipFuncSetAttribute((const void*)gate_kernel,
                      hipFuncAttributeMaxDynamicSharedMemorySize, LDS_BYTES);

  pack_w_kernel<<<dim3(NKC, EEXP / 16), 64, 0, stream>>>(W, whi, wlo);
  gate_kernel<<<TTOK / BM, NTHR, LDS_BYTES, stream>>>(X, whi, wlo, bias, outw, outi);
}